// Round 8
// baseline (361.788 us; speedup 1.0000x reference)
//
#include <hip/hip_runtime.h>
#include <cstdint>
#include <cstddef>
#include <math.h>

#define NN 100000
#define NE 1600000
#define NB ((NN + 255) / 256)   // 391 node buckets (256 nodes each)
#define EB 400                  // phase-A edge blocks
#define EPB (NE / EB)           // 4000 edges per block

// GEMM tiling: 512 threads, 128 nodes/block, per-thread 4 nodes x 4 feats.
#define GT_NODES 128
#define GT_KC 32
#define GT_STRIDE 132   // 128 + 4: keeps 16B alignment of xT rows

typedef unsigned short u16;
typedef int v8i __attribute__((ext_vector_type(8)));
typedef int v4i __attribute__((ext_vector_type(4)));

__device__ __forceinline__ float bf2f(u16 u) {
    union { unsigned int i; float f; } c; c.i = ((unsigned int)u) << 16; return c.f;
}
__device__ __forceinline__ u16 f2bf(float f) {  // round-to-nearest-even
    union { float f; unsigned int i; } c; c.f = f;
    unsigned int lsb = (c.i >> 16) & 1u;
    return (u16)((c.i + 0x7fffu + lsb) >> 16);
}
__device__ __forceinline__ unsigned int pack2(float a, float b) {
    return (unsigned int)f2bf(a) | ((unsigned int)f2bf(b) << 16);
}

// Scalar-pipe loads of 8/4 edge indices: lands in SGPRs, keeps the vmem pipe
// free for the h-row gathers and eliminates per-edge VALU addressing.
// Load + waitcnt fused in ONE asm block (no scheduling hazard).
__device__ __forceinline__ v8i sload8(const int* p) {
    v8i r;
    asm volatile("s_load_dwordx8 %0, %1, 0x0\n\ts_waitcnt lgkmcnt(0)"
                 : "=s"(r) : "s"(p));
    return r;
}
__device__ __forceinline__ v4i sload4(const int* p) {
    v4i r;
    asm volatile("s_load_dwordx4 %0, %1, 0x0\n\ts_waitcnt lgkmcnt(0)"
                 : "=s"(r) : "s"(p));
    return r;
}

// ---------- index-width detection (int64 vs int32 edge_index) ----------
__global__ __launch_bounds__(64) void k_detect(const int* __restrict__ p, int* flag) {
    int nz = 0;
    for (int i = threadIdx.x; i < 1024; i += 64) nz |= (p[2 * i + 1] != 0);
    unsigned long long b = __ballot(nz != 0);
    if (threadIdx.x == 0) *flag = (b == 0ULL) ? 1 : 0;  // 1 => int64
}

__device__ __forceinline__ int load_idx(const void* ei, int isI64, int pos) {
    if (isI64) return (int)((const long long*)ei)[pos];
    return ((const int*)ei)[pos];
}

// ---------- phase A1: per-block bucket histogram ----------
__global__ __launch_bounds__(256) void k_hist(const void* __restrict__ ei,
                                              const int* __restrict__ flag,
                                              int* __restrict__ counts) {
    __shared__ int h[NB];
    for (int i = threadIdx.x; i < NB; i += 256) h[i] = 0;
    __syncthreads();
    int isI64 = *flag;
    int base = blockIdx.x * EPB;
    for (int i = threadIdx.x; i < EPB; i += 256) {
        int d = load_idx(ei, isI64, NE + base + i);
        atomicAdd(&h[d >> 8], 1);
    }
    __syncthreads();
    for (int i = threadIdx.x; i < NB; i += 256) counts[blockIdx.x * NB + i] = h[i];
}

// ---------- phase A2: column prefix over blocks (one block per bucket) ----------
__global__ __launch_bounds__(512) void k_colscan(const int* __restrict__ counts,
                                                 int* __restrict__ pfx,
                                                 int* __restrict__ btot) {
    __shared__ int t[512];
    int j = blockIdx.x;
    int v = (threadIdx.x < EB) ? counts[threadIdx.x * NB + j] : 0;
    t[threadIdx.x] = v;
    __syncthreads();
#pragma unroll
    for (int off = 1; off < 512; off <<= 1) {
        int u = (threadIdx.x >= off) ? t[threadIdx.x - off] : 0;
        __syncthreads();
        t[threadIdx.x] += u;
        __syncthreads();
    }
    if (threadIdx.x < EB) pfx[threadIdx.x * NB + j] = t[threadIdx.x] - v;  // exclusive
    if (threadIdx.x == 511) btot[j] = t[511];
}

// ---------- phase A3: exclusive scan of bucket totals ----------
__global__ __launch_bounds__(512) void k_bucketscan(const int* __restrict__ btot,
                                                    int* __restrict__ bbase) {
    __shared__ int t[512];
    int v = (threadIdx.x < NB) ? btot[threadIdx.x] : 0;
    t[threadIdx.x] = v;
    __syncthreads();
#pragma unroll
    for (int off = 1; off < 512; off <<= 1) {
        int u = (threadIdx.x >= off) ? t[threadIdx.x - off] : 0;
        __syncthreads();
        t[threadIdx.x] += u;
        __syncthreads();
    }
    if (threadIdx.x < NB) bbase[threadIdx.x] = t[threadIdx.x] - v;
    if (threadIdx.x == 511) bbase[NB] = t[511];  // == NE
}

// ---------- phase A4: scatter edges into bucket regions (no global atomics) ----------
// entry = (dstlocal << 17) | src   (src < 2^17, dstlocal < 256)
__global__ __launch_bounds__(256) void k_scatter(const void* __restrict__ ei,
                                                 const int* __restrict__ flag,
                                                 const int* __restrict__ pfx,
                                                 const int* __restrict__ bbase,
                                                 int* __restrict__ csr_tmp) {
    __shared__ int basel[NB];
    __shared__ int cur[NB];
    for (int i = threadIdx.x; i < NB; i += 256) {
        basel[i] = bbase[i] + pfx[blockIdx.x * NB + i];
        cur[i] = 0;
    }
    __syncthreads();
    int isI64 = *flag;
    int base = blockIdx.x * EPB;
    for (int i = threadIdx.x; i < EPB; i += 256) {
        int s = load_idx(ei, isI64, base + i);
        int d = load_idx(ei, isI64, NE + base + i);
        int bkt = d >> 8;
        int slot = basel[bkt] + atomicAdd(&cur[bkt], 1);
        csr_tmp[slot] = ((d & 255) << 17) | s;
    }
}

// ---------- phase B: per-bucket counting sort -> final csr + deg/offs/dis ----------
__global__ __launch_bounds__(256) void k_sort(const int* __restrict__ bbase,
                                              const int* __restrict__ csr_tmp,
                                              int* __restrict__ csr,
                                              int* __restrict__ deg,
                                              int* __restrict__ offs,
                                              float* __restrict__ dis) {
    __shared__ int h[256];
    __shared__ int sc[256];
    __shared__ int cur[256];
    int j = blockIdx.x;
    int s0 = bbase[j], s1 = bbase[j + 1];
    h[threadIdx.x] = 0;
    __syncthreads();
    for (int p = s0 + threadIdx.x; p < s1; p += 256)
        atomicAdd(&h[csr_tmp[p] >> 17], 1);
    __syncthreads();
    int v = h[threadIdx.x];
    sc[threadIdx.x] = v;
    __syncthreads();
#pragma unroll
    for (int off = 1; off < 256; off <<= 1) {
        int u = (threadIdx.x >= off) ? sc[threadIdx.x - off] : 0;
        __syncthreads();
        sc[threadIdx.x] += u;
        __syncthreads();
    }
    int excl = sc[threadIdx.x] - v;
    int node = j * 256 + threadIdx.x;
    if (node < NN) {
        deg[node] = v;
        offs[node] = s0 + excl;
        dis[node] = rsqrtf((float)(v + 1));  // +1 self-loop
    }
    cur[threadIdx.x] = excl;
    __syncthreads();
    for (int p = s0 + threadIdx.x; p < s1; p += 256) {
        int pk = csr_tmp[p];
        int dl = pk >> 17;
        int pos = s0 + atomicAdd(&cur[dl], 1);
        csr[pos] = pk & 0x1FFFF;
    }
}

// ---------- register-tiled GEMM (512 thr, 128 nodes/blk, 4x4/thread) ----------
// g[n][j] = bf16( dis[n] * (act(x)[n][:] @ W[:][j]) )
template <int K, int FR, bool RELU>
__global__ __launch_bounds__(512) void k_gemm(const float* __restrict__ x,
                                              const float* __restrict__ W,
                                              const float* __restrict__ dis,
                                              u16* __restrict__ out) {
    __shared__ float xT[GT_KC * GT_STRIDE];   // 16,896 B
    __shared__ float Wc[GT_KC * 64];          //  8,192 B
    const int tid = threadIdx.x;
    const int r = tid >> 4;    // 0..31 -> nodes r*4 .. r*4+3
    const int c = tid & 15;    // 0..15 -> feats c*4 .. c*4+3
    const int f4 = tid & 7;
    const int nrow = tid >> 3; // 0..63
    const int nbase = blockIdx.x * GT_NODES;

    float acc[4][4];
#pragma unroll
    for (int i = 0; i < 4; ++i)
#pragma unroll
        for (int j = 0; j < 4; ++j) acc[i][j] = 0.f;

    for (int kc = 0; kc < K; kc += GT_KC) {
#pragma unroll
        for (int q = 0; q < 4; ++q) {
            int e = q * 512 + tid;
            int kk = e >> 6, j = e & 63;
            Wc[kk * 64 + j] = (j < FR) ? W[(size_t)(kc + kk) * FR + j] : 0.f;
        }
#pragma unroll
        for (int q = 0; q < 2; ++q) {
            int nl = q * 64 + nrow;
            int n = nbase + nl;
            float4 v = make_float4(0.f, 0.f, 0.f, 0.f);
            if (n < NN) v = *(const float4*)(x + (size_t)n * K + kc + f4 * 4);
            if (RELU) {
                v.x = fmaxf(v.x, 0.f); v.y = fmaxf(v.y, 0.f);
                v.z = fmaxf(v.z, 0.f); v.w = fmaxf(v.w, 0.f);
            }
            xT[(f4 * 4 + 0) * GT_STRIDE + nl] = v.x;
            xT[(f4 * 4 + 1) * GT_STRIDE + nl] = v.y;
            xT[(f4 * 4 + 2) * GT_STRIDE + nl] = v.z;
            xT[(f4 * 4 + 3) * GT_STRIDE + nl] = v.w;
        }
        __syncthreads();
#pragma unroll 8
        for (int kk = 0; kk < GT_KC; ++kk) {
            float4 a = *(const float4*)&xT[kk * GT_STRIDE + r * 4];
            float4 w = *(const float4*)&Wc[kk * 64 + c * 4];
            float xa[4] = {a.x, a.y, a.z, a.w};
            float wb[4] = {w.x, w.y, w.z, w.w};
#pragma unroll
            for (int i = 0; i < 4; ++i)
#pragma unroll
                for (int j = 0; j < 4; ++j)
                    acc[i][j] = fmaf(xa[i], wb[j], acc[i][j]);
        }
        __syncthreads();
    }
    if (c * 4 < FR) {
#pragma unroll
        for (int i = 0; i < 4; ++i) {
            int n = nbase + r * 4 + i;
            if (n < NN) {
                float dv = dis[n];
                uint2 o;
                o.x = pack2(dv * acc[i][0], dv * acc[i][1]);
                o.y = pack2(dv * acc[i][2], dv * acc[i][3]);
                *(uint2*)(out + (size_t)n * FR + c * 4) = o;
            }
        }
    }
}

// ---------- gather aggregation (unweighted sum of pre-scaled bf16 g) ----------
// out[n][f] = dis[n] * ( g[n][f] + sum_e g[src_e][f] ) + b[f]
// Edge indices stream over the SCALAR pipe (s_load_dwordx8) -> row bases are
// SGPR pairs; h-gather is global_load_ushort saddr+voffset: 2 VALU/edge total.
template <int F, bool SOFTMAX>
__global__ __launch_bounds__(256) void k_gather(const int* __restrict__ offs,
                                                const int* __restrict__ deg,
                                                const int* __restrict__ csr,
                                                const float* __restrict__ dis,
                                                const u16* __restrict__ g,
                                                const float* __restrict__ b,
                                                float* __restrict__ out) {
    int n = blockIdx.x * 4 + (threadIdx.x >> 6);
    unsigned f = threadIdx.x & 63;
    if (n >= NN) return;
    unsigned fc = (f < (unsigned)F) ? f : 0u;
    int start = __builtin_amdgcn_readfirstlane(offs[n]);
    int len   = __builtin_amdgcn_readfirstlane(deg[n]);
    float dvn = dis[n];
    float bf  = b[fc];
    float acc = bf2f(g[(unsigned)n * F + fc]);  // self-loop (pre-scaled)
    int i = 0;
    for (; i + 8 <= len; i += 8) {
        v8i ix = sload8(csr + start + i);
        u16 h0 = g[(unsigned)ix[0] * F + fc];
        u16 h1 = g[(unsigned)ix[1] * F + fc];
        u16 h2 = g[(unsigned)ix[2] * F + fc];
        u16 h3 = g[(unsigned)ix[3] * F + fc];
        u16 h4 = g[(unsigned)ix[4] * F + fc];
        u16 h5 = g[(unsigned)ix[5] * F + fc];
        u16 h6 = g[(unsigned)ix[6] * F + fc];
        u16 h7 = g[(unsigned)ix[7] * F + fc];
        acc += bf2f(h0) + bf2f(h1) + bf2f(h2) + bf2f(h3)
             + bf2f(h4) + bf2f(h5) + bf2f(h6) + bf2f(h7);
    }
    if (i + 4 <= len) {
        v4i ix = sload4(csr + start + i);
        u16 h0 = g[(unsigned)ix[0] * F + fc];
        u16 h1 = g[(unsigned)ix[1] * F + fc];
        u16 h2 = g[(unsigned)ix[2] * F + fc];
        u16 h3 = g[(unsigned)ix[3] * F + fc];
        acc += bf2f(h0) + bf2f(h1) + bf2f(h2) + bf2f(h3);
        i += 4;
    }
    for (; i < len; ++i) {
        int s0 = __builtin_amdgcn_readfirstlane(csr[start + i]);
        acc += bf2f(g[(unsigned)s0 * F + fc]);
    }
    float v = dvn * acc + bf;
    if (!SOFTMAX) {
        if (f < (unsigned)F) out[(size_t)n * F + f] = v;
    } else {
        float vv = (f < (unsigned)F) ? v : -INFINITY;
        float m = vv;
#pragma unroll
        for (int off = 32; off; off >>= 1) m = fmaxf(m, __shfl_xor(m, off));
        float ex = (f < (unsigned)F) ? __expf(vv - m) : 0.f;
        float sum = ex;
#pragma unroll
        for (int off = 32; off; off >>= 1) sum += __shfl_xor(sum, off);
        if (f < (unsigned)F) out[(size_t)n * F + f] = vv - m - logf(sum);
    }
}

extern "C" void kernel_launch(void* const* d_in, const int* in_sizes, int n_in,
                              void* d_out, int out_size, void* d_ws, size_t ws_size,
                              hipStream_t stream) {
    const float* x  = (const float*)d_in[0];
    const void*  ei = d_in[1];
    const float* W1 = (const float*)d_in[2];
    const float* b1 = (const float*)d_in[3];
    const float* W2 = (const float*)d_in[4];
    const float* b2 = (const float*)d_in[5];
    const float* W3 = (const float*)d_in[6];
    const float* b3 = (const float*)d_in[7];
    float* out = (float*)d_out;

    char* ws = (char*)d_ws;
    size_t off = 0;
    auto alloc = [&](size_t bytes) { void* p = ws + off; off += (bytes + 255) & ~255ULL; return p; };
    int*   flag    = (int*)alloc(4);
    int*   counts  = (int*)alloc((size_t)EB * NB * 4);
    int*   pfx     = (int*)alloc((size_t)EB * NB * 4);
    int*   btot    = (int*)alloc(NB * 4);
    int*   bbase   = (int*)alloc((NB + 1) * 4);
    int*   deg     = (int*)alloc(NN * 4);
    float* dis     = (float*)alloc(NN * 4);
    int*   offs    = (int*)alloc(NN * 4);
    int*   csr_tmp = (int*)alloc((size_t)NE * 4);
    int*   csr     = (int*)alloc((size_t)NE * 4);
    u16*   gbuf    = (u16*)alloc((size_t)NN * 64 * 2);   // bf16 staging (12.8 MB)
    float* act     = (float*)alloc((size_t)NN * 64 * 4); // fp32 inter-layer activations

    // CSR build (deterministic two-phase counting sort; no global atomics)
    k_detect<<<1, 64, 0, stream>>>((const int*)ei, flag);
    k_hist<<<EB, 256, 0, stream>>>(ei, flag, counts);
    k_colscan<<<NB, 512, 0, stream>>>(counts, pfx, btot);
    k_bucketscan<<<1, 512, 0, stream>>>(btot, bbase);
    k_scatter<<<EB, 256, 0, stream>>>(ei, flag, pfx, bbase, csr_tmp);
    k_sort<<<NB, 256, 0, stream>>>(bbase, csr_tmp, csr, deg, offs, dis);

    const int gemm_grid = (NN + GT_NODES - 1) / GT_NODES;   // 782
    const int gather_grid = (NN + 3) / 4;

    // layer 1: g1 = bf16(dis*(x@W1)); out1 = dis*(sum g1) + b1  (ReLU fused into next gemm)
    k_gemm<128, 64, false><<<gemm_grid, 512, 0, stream>>>(x, W1, dis, gbuf);
    k_gather<64, false><<<gather_grid, 256, 0, stream>>>(offs, deg, csr, dis, gbuf, b1, act);

    // layer 2
    k_gemm<64, 64, true><<<gemm_grid, 512, 0, stream>>>(act, W2, dis, gbuf);
    k_gather<64, false><<<gather_grid, 256, 0, stream>>>(offs, deg, csr, dis, gbuf, b2, act);

    // layer 3 + fused log_softmax
    k_gemm<64, 40, true><<<gemm_grid, 512, 0, stream>>>(act, W3, dis, gbuf);
    k_gather<40, true><<<gather_grid, 256, 0, stream>>>(offs, deg, csr, dis, gbuf, b3, out);
}